// Round 15
// baseline (209.983 us; speedup 1.0000x reference)
//
#include <hip/hip_runtime.h>
#include <math.h>

#define DTC 0.1f

typedef _Float16 half8 __attribute__((ext_vector_type(8)));
typedef _Float16 half4v __attribute__((ext_vector_type(4)));
typedef float f32x4 __attribute__((ext_vector_type(4)));
typedef float f32x2 __attribute__((ext_vector_type(2)));

__device__ __forceinline__ float fast_tanh(float x) {
  const float e = __expf(2.f * x);
  const float r = __builtin_amdgcn_rcpf(e + 1.f);
  return fmaf(-2.f, r, 1.f);
}

// LDS-only barrier: own ds ops retired (lgkmcnt 0) -> s_barrier.
// Unlike __syncthreads(), does NOT drain vmcnt — in-flight global loads
// (next-phase bf ring, bias vectors) survive the phase boundary (T4).
__device__ __forceinline__ void bar_lds() {
  asm volatile("s_waitcnt lgkmcnt(0)" ::: "memory");
  __builtin_amdgcn_s_barrier();
}

// ================= precompute =================================================

// Wh = fp16(W) ; Wt = fp16(W^T) ; crm[l][j] = -0.09 * sum_k b_{l+2}[k] W_l[k][j]
__global__ __launch_bounds__(256) void k_prep(
    const float* __restrict__ W0, const float* __restrict__ W1,
    const float* __restrict__ W2, const float* __restrict__ W3,
    const float* __restrict__ b2, const float* __restrict__ b3,
    const float* __restrict__ b4,
    _Float16* __restrict__ Wh, _Float16* __restrict__ Wt,
    float* __restrict__ crm) {
  const float* Ws[4] = {W0, W1, W2, W3};
  const int bid = blockIdx.x, tid = threadIdx.x;
  if (bid < 128) {
    const int t = bid * 256 + tid;
    const float* W = Ws[(t * 8) >> 16];
    const int off = (t * 8) & 65535;
    const float4 a = *(const float4*)&W[off];
    const float4 b = *(const float4*)&W[off + 4];
    half8 h;
    h[0] = (_Float16)a.x; h[1] = (_Float16)a.y; h[2] = (_Float16)a.z; h[3] = (_Float16)a.w;
    h[4] = (_Float16)b.x; h[5] = (_Float16)b.y; h[6] = (_Float16)b.z; h[7] = (_Float16)b.w;
    *(half8*)&Wh[t * 8] = h;
  } else if (bid < 384) {
    __shared__ float sh[32][33];
    const int b2i = bid - 128;
    const int l = b2i >> 6, t64 = b2i & 63;
    const int r0 = (t64 >> 3) * 32, c0 = (t64 & 7) * 32;
    const float* W = Ws[l];
    const int i = tid >> 5, j = tid & 31;
#pragma unroll
    for (int p = 0; p < 4; ++p)
      sh[p * 8 + i][j] = W[(r0 + p * 8 + i) * 256 + c0 + j];
    __syncthreads();
#pragma unroll
    for (int p = 0; p < 4; ++p)
      Wt[l * 65536 + (c0 + p * 8 + i) * 256 + r0 + j] = (_Float16)sh[j][p * 8 + i];
  } else {
    const int l = bid - 384;
    const float* W = Ws[l];
    const float* b = (l == 0) ? b2 : (l == 1) ? b3 : b4;
    float s = 0.f;
#pragma unroll 8
    for (int k = 0; k < 256; ++k) s = fmaf(b[k], W[k * 256 + tid], s);
    crm[l * 256 + tid] = -0.09f * s;
  }
}

// C = scale*(A@B^T) [+ I - Eadd]   per layer (blockIdx.z), 256x256, fp16 rm out
__global__ __launch_bounds__(256) void k_smm3(const _Float16* __restrict__ A,
                                              const _Float16* __restrict__ B,
                                              const _Float16* __restrict__ Eadd,
                                              _Float16* __restrict__ C,
                                              float scale, int addI) {
  const int tid = threadIdx.x, wave = tid >> 6, lane = tid & 63;
  const int quad = lane >> 4, l16 = lane & 15;
  const int l = blockIdx.z;
  const _Float16* Al = A + (size_t)l * 65536;
  const _Float16* Bl = B + (size_t)l * 65536;
  _Float16* Cl = C + (size_t)l * 65536;
  const int m0 = blockIdx.y * 64 + wave * 16, n0 = blockIdx.x * 64;
  f32x4 acc[4] = {};
#pragma unroll
  for (int kt = 0; kt < 8; ++kt) {
    const half8 af = *(const half8*)&Al[(m0 + l16) * 256 + kt * 32 + quad * 8];
#pragma unroll
    for (int ni = 0; ni < 4; ++ni) {
      const half8 bf = *(const half8*)&Bl[(n0 + ni * 16 + l16) * 256 + kt * 32 + quad * 8];
      acc[ni] = __builtin_amdgcn_mfma_f32_16x16x32_f16(af, bf, acc[ni], 0, 0, 0);
    }
  }
#pragma unroll
  for (int ni = 0; ni < 4; ++ni)
#pragma unroll
    for (int r = 0; r < 4; ++r) {
      const int row = m0 + quad * 4 + r, col = n0 + ni * 16 + l16;
      float v = scale * acc[ni][r];
      if (addI) v += (row == col ? 1.f : 0.f) - (float)(Eadd + (size_t)l * 65536)[row * 256 + col];
      Cl[row * 256 + col] = (_Float16)v;
    }
}

// Destination-mapped coalesced packing of all B-frag weight buffers.
// chunk = 16B of 8 halves; packed idx = ((ntile*NKT+kt)*64 + lane)*8 + j
// holds B[n=ntile*16+(lane&15)][k=kt*32+(lane>>4)*8+j]
__global__ __launch_bounds__(256) void k_pack(
    const _Float16* __restrict__ Ph, const _Float16* __restrict__ Qt,
    const _Float16* __restrict__ Wt, const float* __restrict__ Wi,
    const float* __restrict__ Wo,
    _Float16* __restrict__ PQP, _Float16* __restrict__ RmP,
    _Float16* __restrict__ WiP, _Float16* __restrict__ WoP) {
  const int t = blockIdx.x * 256 + threadIdx.x;
  if (t < 65536) {  // PQP: NKT=16, kt<8 -> -P (sym), kt>=8 -> Qt
    const int l = t >> 14, c = t & 16383;
    const int ntile = c >> 10, kt = (c >> 6) & 15, lb = c & 63;
    const int n = ntile * 16 + (lb & 15);
    const int kq = (lb >> 4) * 8;
    half8 h;
    if (kt < 8) {
      h = *(const half8*)&Ph[(size_t)l * 65536 + n * 256 + kt * 32 + kq];
#pragma unroll
      for (int j = 0; j < 8; ++j) h[j] = -h[j];
    } else {
      h = *(const half8*)&Qt[(size_t)l * 65536 + n * 256 + (kt - 8) * 32 + kq];
    }
    *(half8*)&PQP[(size_t)t * 8] = h;
  } else if (t < 90112) {  // RmP: NKT=8, B[n][k] = -0.9*Wt[n][k]
    const int tt = t - 65536;
    const int l = tt >> 13, c = tt & 8191;
    const int ntile = c >> 9, kt = (c >> 6) & 7, lb = c & 63;
    const int n = ntile * 16 + (lb & 15);
    const int k0 = kt * 32 + (lb >> 4) * 8;
    half8 h = *(const half8*)&Wt[(size_t)l * 65536 + n * 256 + k0];
#pragma unroll
    for (int j = 0; j < 8; ++j) h[j] = (_Float16)(-0.9f * (float)h[j]);
    *(half8*)&RmP[(size_t)tt * 8] = h;
  } else if (t < 98304) {  // WiP: NKT=8, B[n][k] = Wi[n][k]
    const int c = t - 90112;
    const int ntile = c >> 9, kt = (c >> 6) & 7, lb = c & 63;
    const int n = ntile * 16 + (lb & 15);
    const int k0 = kt * 32 + (lb >> 4) * 8;
    const float4 a = *(const float4*)&Wi[n * 256 + k0];
    const float4 b = *(const float4*)&Wi[n * 256 + k0 + 4];
    half8 h;
    h[0] = (_Float16)a.x; h[1] = (_Float16)a.y; h[2] = (_Float16)a.z; h[3] = (_Float16)a.w;
    h[4] = (_Float16)b.x; h[5] = (_Float16)b.y; h[6] = (_Float16)b.z; h[7] = (_Float16)b.w;
    *(half8*)&WiP[(size_t)c * 8] = h;
  } else {  // WoP: NKT=8, classes padded to 16
    const int c = t - 98304;  // 0..511
    const int kt = c >> 6, lb = c & 63;
    const int n = lb & 15;
    const int k0 = kt * 32 + (lb >> 4) * 8;
    half8 h;
#pragma unroll
    for (int j = 0; j < 8; ++j) h[j] = (_Float16)((n < 10) ? Wo[n * 256 + k0 + j] : 0.f);
    *(half8*)&WoP[(size_t)c * 8] = h;
  }
}

// ================= fused persistent batch kernel =============================

// FRAGMENT-PACKED A-tile layout (R13): fragment f = kt*4 + mi, 1024B each;
// within fragment slot = MFMA lane, 16B/slot. All LDS accesses are
// compile-time offsets from a per-thread base.
// R14 geometry: wave tile 64x64 (mi=4, ni=4), 4 waves, 64-row slab.
// R15: bf ring preloaded by CALLER (possibly before the phase barrier, so
// L2 latency hides under the previous epilogue), counted-wait barriers.

// preload ring slots 0..2 for the next GEMM phase
template <int NKT>
__device__ __forceinline__ void preB(const _Float16* __restrict__ Bp,
                                     half8 bf[4][4], int wave, int lane) {
#pragma unroll
  for (int s = 0; s < 3; ++s)
#pragma unroll
    for (int ni = 0; ni < 4; ++ni)
      bf[s][ni] = *(const half8*)&Bp[(((wave * 4 + ni) * NKT + s) * 64 + lane) * 8];
}

template <int NKT, bool DUAL>
__device__ __forceinline__ void gemm_k(const _Float16* __restrict__ Bp,
                                       const _Float16* A1, const _Float16* A2,
                                       f32x4* acc, half8 bf[4][4],
                                       int wave, int lane) {
  const char* a1b = (const char*)A1 + lane * 16;
  const char* a2b = (const char*)A2 + lane * 16;
#pragma unroll
  for (int kt = 0; kt < NKT; ++kt) {
    const int s = kt & 3;
    if (kt + 3 < NKT) {
#pragma unroll
      for (int ni = 0; ni < 4; ++ni)
        bf[(kt + 3) & 3][ni] =
            *(const half8*)&Bp[(((wave * 4 + ni) * NKT + kt + 3) * 64 + lane) * 8];
    }
    const char* Ab = (DUAL && kt >= NKT / 2) ? a2b : a1b;
    const int akt = DUAL ? (kt & (NKT / 2 - 1)) : kt;
    half8 af[4];
#pragma unroll
    for (int mi = 0; mi < 4; ++mi)
      af[mi] = *(const half8*)(Ab + (akt * 4 + mi) * 1024);
    __builtin_amdgcn_s_setprio(1);
#pragma unroll
    for (int mi = 0; mi < 4; ++mi)
#pragma unroll
      for (int ni = 0; ni < 4; ++ni)
        acc[mi * 4 + ni] = __builtin_amdgcn_mfma_f32_16x16x32_f16(
            bf[s][ni], af[mi], acc[mi * 4 + ni], 0, 0, 0);
    __builtin_amdgcn_s_setprio(0);
  }
}

// 64-row slab, 4 waves (256 thr), 2 blocks/CU (LDS 64KB), 2 waves/SIMD.
// launch_bounds(256,2): VGPR cap 256. Budget: acc 64 + ring 64 (live
// across epilogues for cross-barrier preload) + uph 32 + af 16 + bias 16
// + misc ~20 = ~212. WRITE_SIZE is the spill tell — must stay ~1.28MB.
__global__ __launch_bounds__(256, 2) void k_fused(
    const float* __restrict__ x, const _Float16* __restrict__ WiP,
    const _Float16* __restrict__ PQP, const _Float16* __restrict__ RmP,
    const _Float16* __restrict__ WoP, const float* __restrict__ bi,
    const float* __restrict__ b1, const float* __restrict__ b2,
    const float* __restrict__ b3, const float* __restrict__ b4,
    const float* __restrict__ crm, const float* __restrict__ bo,
    float* __restrict__ out) {
  __shared__ __align__(16) _Float16 A1[64 * 256];
  __shared__ __align__(16) _Float16 A2[64 * 256];
  const int tid = threadIdx.x;
  const int wave = tid >> 6, lane = tid & 63;
  const int quad = lane >> 4, l16 = lane & 15;
  const int m0 = blockIdx.x * 64;

  // ---- stage x: fp32 HBM -> fp16 fragment-packed LDS (A1) ----
#pragma unroll
  for (int kk = 0; kk < 2; ++kk) {
    const int kt = wave + kk * 4;
#pragma unroll
    for (int mi = 0; mi < 4; ++mi) {
      const size_t gb = (size_t)(m0 + mi * 16 + l16) * 256 + kt * 32 + quad * 8;
      const float4 a = *(const float4*)&x[gb];
      const float4 b = *(const float4*)&x[gb + 4];
      half8 h;
      h[0] = (_Float16)a.x; h[1] = (_Float16)a.y; h[2] = (_Float16)a.z; h[3] = (_Float16)a.w;
      h[4] = (_Float16)b.x; h[5] = (_Float16)b.y; h[6] = (_Float16)b.z; h[7] = (_Float16)b.w;
      *(half8*)((char*)A1 + ((kt * 4 + mi) * 64 + lane) * 16) = h;
    }
  }

  f32x4 acc[16];
  const f32x4 zero = {0.f, 0.f, 0.f, 0.f};
  half4v uph[16];
  half8 ring[4][4];

  // ring for GEMM0 issued BEFORE the stage barrier (loads fly across it)
  preB<8>(WiP, ring, wave, lane);
  bar_lds();

  // per-thread epilogue base: wave owns cols [wave*64, wave*64+64) ->
  // addr = base + (ni>>1)*4096 + mi*1024 + (ni&1)*512
  const int ebase = wave * 8192 + (quad >> 1) * 256 + l16 * 16 + (quad & 1) * 8;
  char* e1 = (char*)A1 + ebase;
  char* e2 = (char*)A2 + ebase;

  // ---- GEMM0: z = x@WiT ; A1 = r1 = z+bi+0.1*b1 ; A2 = r2 = tanh(z+bi) ----
#pragma unroll
  for (int t = 0; t < 16; ++t) acc[t] = zero;
  gemm_k<8, false>(WiP, A1, A1, acc, ring, wave, lane);
  // bias first (in-order vmcnt: waiting on these leaves ring outstanding),
  // then next-phase ring — both in flight across the two barriers below.
  f32x4 bi4[4], b14[4];
#pragma unroll
  for (int ni = 0; ni < 4; ++ni) {
    const int col0 = wave * 64 + ni * 16 + quad * 4;
    bi4[ni] = *(const f32x4*)&bi[col0];
    b14[ni] = *(const f32x4*)&b1[col0];
  }
  preB<16>(PQP, ring, wave, lane);
  bar_lds();  // protect A1 overwrite (other waves done reading)
#pragma unroll
  for (int ni = 0; ni < 4; ++ni) {
#pragma unroll
    for (int mi = 0; mi < 4; ++mi) {
      const int off = (ni >> 1) * 4096 + mi * 1024 + (ni & 1) * 512;
      half4v h1, h2;
#pragma unroll
      for (int r = 0; r < 4; ++r) {
        const float z = acc[mi * 4 + ni][r] + bi4[ni][r];
        h1[r] = (_Float16)(z + DTC * b14[ni][r]);
        h2[r] = (_Float16)fast_tanh(z);
      }
      *(half4v*)(e1 + off) = h1;
      *(half4v*)(e2 + off) = h2;
    }
  }
  bar_lds();

  // ---- 4 transport layers ----
#pragma unroll 1
  for (int l = 0; l < 4; ++l) {
    // u' = r1@Pm + r2@Q   (K=512); ring preloaded by previous epilogue
#pragma unroll
    for (int t = 0; t < 16; ++t) acc[t] = zero;
    gemm_k<16, true>(PQP + (size_t)l * 131072, A1, A2, acc, ring, wave, lane);
    const float* bn = (l == 0) ? b2 : (l == 1) ? b3 : b4;
    f32x4 bn4[4];
#pragma unroll
    for (int ni = 0; ni < 4; ++ni) {
      bn4[ni] = zero;
      if (l < 3) bn4[ni] = DTC * (*(const f32x4*)&bn[wave * 64 + ni * 16 + quad * 4]);
    }
    if (l < 3) preB<8>(RmP + (size_t)l * 65536, ring, wave, lane);
    bar_lds();
#pragma unroll
    for (int ni = 0; ni < 4; ++ni) {
#pragma unroll
      for (int mi = 0; mi < 4; ++mi) {
        const int off = (ni >> 1) * 4096 + mi * 1024 + (ni & 1) * 512;
        half4v hu, h1;
#pragma unroll
        for (int r = 0; r < 4; ++r) {
          const float u = acc[mi * 4 + ni][r];
          hu[r] = (_Float16)u;
          h1[r] = (_Float16)(u + bn4[ni][r]);
        }
        uph[mi * 4 + ni] = hu;
        *(half4v*)(e1 + off) = h1;   // r1 for next layer / v'-GEMM input
      }
    }
    bar_lds();
    if (l < 3) {
      // v' = r1_next@Rm - crm - r2_old ; new r2 = (v' + 10 tanh u')/11
#pragma unroll
      for (int t = 0; t < 16; ++t) acc[t] = zero;
      gemm_k<8, false>(RmP + (size_t)l * 65536, A1, A1, acc, ring, wave, lane);
      f32x4 cc4[4];
#pragma unroll
      for (int ni = 0; ni < 4; ++ni)
        cc4[ni] = *(const f32x4*)&crm[l * 256 + wave * 64 + ni * 16 + quad * 4];
      preB<16>(PQP + (size_t)(l + 1) * 131072, ring, wave, lane);
      // no barrier needed before v-epilogue: v-GEMM read only A1; the
      // epilogue touches only this thread's own A2 slots.
#pragma unroll
      for (int ni = 0; ni < 4; ++ni) {
#pragma unroll
        for (int mi = 0; mi < 4; ++mi) {
          const int off = (ni >> 1) * 4096 + mi * 1024 + (ni & 1) * 512;
          const half4v r2o = *(const half4v*)(e2 + off);
          half4v nr2;
#pragma unroll
          for (int r = 0; r < 4; ++r) {
            const float vp = acc[mi * 4 + ni][r] - cc4[ni][r] - (float)r2o[r];
            nr2[r] = (_Float16)((vp + 10.f * fast_tanh((float)uph[mi * 4 + ni][r])) * (1.f / 11.f));
          }
          *(half4v*)(e2 + off) = nr2;
        }
      }
      bar_lds();
    }
  }

  // ---- head: logits = z@Wo^T + bo (swapped MFMA); softmax ----
  // layer-3 epilogue wrote A1 = u'; last bar_lds in the loop synced it.
  {
    f32x4 acch = zero;
#pragma unroll
    for (int kt = 0; kt < 8; ++kt) {
      const half8 af = *(const half8*)((const char*)A1 +
                                       ((kt * 4 + wave) * 64 + lane) * 16);
      const half8 bfr = *(const half8*)&WoP[(kt * 64 + lane) * 8];
      acch = __builtin_amdgcn_mfma_f32_16x16x32_f16(bfr, af, acch, 0, 0, 0);
    }
    float v4[4];
    float mx = -3.0e38f;
#pragma unroll
    for (int r = 0; r < 4; ++r) {
      const int cls = quad * 4 + r;
      const float v = acch[r] + ((cls < 10) ? bo[cls] : -3.0e38f);
      v4[r] = v;
      mx = fmaxf(mx, v);
    }
    mx = fmaxf(mx, __shfl_xor(mx, 16, 64));
    mx = fmaxf(mx, __shfl_xor(mx, 32, 64));
    float e4[4], s = 0.f;
#pragma unroll
    for (int r = 0; r < 4; ++r) {
      e4[r] = __expf(v4[r] - mx);
      s += e4[r];
    }
    s += __shfl_xor(s, 16, 64);
    s += __shfl_xor(s, 32, 64);
    const float rs = __builtin_amdgcn_rcpf(s);
    float* op = &out[(size_t)(m0 + wave * 16 + l16) * 10 + quad * 4];
    if (quad < 2) {
      f32x2 p0 = {e4[0] * rs, e4[1] * rs};
      f32x2 p1 = {e4[2] * rs, e4[3] * rs};
      *(f32x2*)op = p0;
      *(f32x2*)(op + 2) = p1;
    } else if (quad == 2) {
      f32x2 p0 = {e4[0] * rs, e4[1] * rs};
      *(f32x2*)op = p0;
    }
  }
}

// ================= launcher ==================================================

extern "C" void kernel_launch(void* const* d_in, const int* in_sizes, int n_in,
                              void* d_out, int out_size, void* d_ws, size_t ws_size,
                              hipStream_t stream) {
  const float* x  = (const float*)d_in[0];
  const float* Wi = (const float*)d_in[1];
  const float* bi = (const float*)d_in[2];
  const float* W[4] = {(const float*)d_in[3], (const float*)d_in[5],
                       (const float*)d_in[7], (const float*)d_in[9]};
  const float* b[4] = {(const float*)d_in[4], (const float*)d_in[6],
                       (const float*)d_in[8], (const float*)d_in[10]};
  const float* Wo = (const float*)d_in[11];
  const float* bo = (const float*)d_in[12];
  float* out = (float*)d_out;

  const int Bsz = in_sizes[0] / 256;  // 32768

  _Float16* hb = (_Float16*)d_ws;
  _Float16* WiP = hb;                   // 65536
  _Float16* WoP = hb + 65536;           // 4096
  _Float16* PQP = hb + 69632;           // 524288
  _Float16* RmP = hb + 593920;          // 196608
  _Float16* Wh  = hb + 790528;          // 262144
  _Float16* Wt  = hb + 1052672;         // 262144
  _Float16* Eh  = hb + 1314816;         // 262144
  _Float16* Ph  = hb + 1576960;         // 262144
  _Float16* Qt  = hb + 1839104;         // 262144
  float* crm = (float*)(hb + 2101248);  // 768 floats

  const dim3 g64(4, 4, 4);
  k_prep<<<387, 256, 0, stream>>>(W[0], W[1], W[2], W[3], b[1], b[2], b[3],
                                  Wh, Wt, crm);
  k_smm3<<<g64, 256, 0, stream>>>(Wh, Wh, nullptr, Eh, 0.01f, 0);  // E = DT^2 W W^T
  k_smm3<<<g64, 256, 0, stream>>>(Eh, Eh, Eh, Ph, 1.0f, 1);        // P = I - E + E^2
  k_smm3<<<g64, 256, 0, stream>>>(Ph, Wt, nullptr, Qt, DTC, 0);    // Qt = 0.1 P@W
  k_pack<<<386, 256, 0, stream>>>(Ph, Qt, Wt, Wi, Wo, PQP, RmP, WiP, WoP);

  k_fused<<<Bsz / 64, 256, 0, stream>>>(x, WiP, PQP, RmP, WoP, bi,
                                        b[0], b[1], b[2], b[3], crm, bo, out);
}

// Round 16
// 195.543 us; speedup vs baseline: 1.0738x; 1.0738x over previous
//
#include <hip/hip_runtime.h>
#include <math.h>

#define DTC 0.1f

typedef _Float16 half8 __attribute__((ext_vector_type(8)));
typedef _Float16 half4v __attribute__((ext_vector_type(4)));
typedef float f32x4 __attribute__((ext_vector_type(4)));
typedef float f32x2 __attribute__((ext_vector_type(2)));

__device__ __forceinline__ float fast_tanh(float x) {
  const float e = __expf(2.f * x);
  const float r = __builtin_amdgcn_rcpf(e + 1.f);
  return fmaf(-2.f, r, 1.f);
}

// LDS-only barrier: own ds ops retired (lgkmcnt 0) -> s_barrier.
// Unlike __syncthreads(), does NOT drain vmcnt — in-flight global loads
// (next-phase bf ring, bias vectors) survive the phase boundary (T4).
__device__ __forceinline__ void bar_lds() {
  asm volatile("s_waitcnt lgkmcnt(0)" ::: "memory");
  __builtin_amdgcn_s_barrier();
}

// ================= precompute =================================================

// Wh = fp16(W) ; Wt = fp16(W^T) ; crm[l][j] = -0.09 * sum_k b_{l+2}[k] W_l[k][j]
__global__ __launch_bounds__(256) void k_prep(
    const float* __restrict__ W0, const float* __restrict__ W1,
    const float* __restrict__ W2, const float* __restrict__ W3,
    const float* __restrict__ b2, const float* __restrict__ b3,
    const float* __restrict__ b4,
    _Float16* __restrict__ Wh, _Float16* __restrict__ Wt,
    float* __restrict__ crm) {
  const float* Ws[4] = {W0, W1, W2, W3};
  const int bid = blockIdx.x, tid = threadIdx.x;
  if (bid < 128) {
    const int t = bid * 256 + tid;
    const float* W = Ws[(t * 8) >> 16];
    const int off = (t * 8) & 65535;
    const float4 a = *(const float4*)&W[off];
    const float4 b = *(const float4*)&W[off + 4];
    half8 h;
    h[0] = (_Float16)a.x; h[1] = (_Float16)a.y; h[2] = (_Float16)a.z; h[3] = (_Float16)a.w;
    h[4] = (_Float16)b.x; h[5] = (_Float16)b.y; h[6] = (_Float16)b.z; h[7] = (_Float16)b.w;
    *(half8*)&Wh[t * 8] = h;
  } else if (bid < 384) {
    __shared__ float sh[32][33];
    const int b2i = bid - 128;
    const int l = b2i >> 6, t64 = b2i & 63;
    const int r0 = (t64 >> 3) * 32, c0 = (t64 & 7) * 32;
    const float* W = Ws[l];
    const int i = tid >> 5, j = tid & 31;
#pragma unroll
    for (int p = 0; p < 4; ++p)
      sh[p * 8 + i][j] = W[(r0 + p * 8 + i) * 256 + c0 + j];
    __syncthreads();
#pragma unroll
    for (int p = 0; p < 4; ++p)
      Wt[l * 65536 + (c0 + p * 8 + i) * 256 + r0 + j] = (_Float16)sh[j][p * 8 + i];
  } else {
    const int l = bid - 384;
    const float* W = Ws[l];
    const float* b = (l == 0) ? b2 : (l == 1) ? b3 : b4;
    float s = 0.f;
#pragma unroll 8
    for (int k = 0; k < 256; ++k) s = fmaf(b[k], W[k * 256 + tid], s);
    crm[l * 256 + tid] = -0.09f * s;
  }
}

// C = scale*(A@B^T) [+ I - Eadd]   per layer (blockIdx.z), 256x256, fp16 rm out
__global__ __launch_bounds__(256) void k_smm3(const _Float16* __restrict__ A,
                                              const _Float16* __restrict__ B,
                                              const _Float16* __restrict__ Eadd,
                                              _Float16* __restrict__ C,
                                              float scale, int addI) {
  const int tid = threadIdx.x, wave = tid >> 6, lane = tid & 63;
  const int quad = lane >> 4, l16 = lane & 15;
  const int l = blockIdx.z;
  const _Float16* Al = A + (size_t)l * 65536;
  const _Float16* Bl = B + (size_t)l * 65536;
  _Float16* Cl = C + (size_t)l * 65536;
  const int m0 = blockIdx.y * 64 + wave * 16, n0 = blockIdx.x * 64;
  f32x4 acc[4] = {};
#pragma unroll
  for (int kt = 0; kt < 8; ++kt) {
    const half8 af = *(const half8*)&Al[(m0 + l16) * 256 + kt * 32 + quad * 8];
#pragma unroll
    for (int ni = 0; ni < 4; ++ni) {
      const half8 bf = *(const half8*)&Bl[(n0 + ni * 16 + l16) * 256 + kt * 32 + quad * 8];
      acc[ni] = __builtin_amdgcn_mfma_f32_16x16x32_f16(af, bf, acc[ni], 0, 0, 0);
    }
  }
#pragma unroll
  for (int ni = 0; ni < 4; ++ni)
#pragma unroll
    for (int r = 0; r < 4; ++r) {
      const int row = m0 + quad * 4 + r, col = n0 + ni * 16 + l16;
      float v = scale * acc[ni][r];
      if (addI) v += (row == col ? 1.f : 0.f) - (float)(Eadd + (size_t)l * 65536)[row * 256 + col];
      Cl[row * 256 + col] = (_Float16)v;
    }
}

// Destination-mapped coalesced packing of all B-frag weight buffers.
// chunk = 16B of 8 halves; packed idx = ((ntile*NKT+kt)*64 + lane)*8 + j
// holds B[n=ntile*16+(lane&15)][k=kt*32+(lane>>4)*8+j]
__global__ __launch_bounds__(256) void k_pack(
    const _Float16* __restrict__ Ph, const _Float16* __restrict__ Qt,
    const _Float16* __restrict__ Wt, const float* __restrict__ Wi,
    const float* __restrict__ Wo,
    _Float16* __restrict__ PQP, _Float16* __restrict__ RmP,
    _Float16* __restrict__ WiP, _Float16* __restrict__ WoP) {
  const int t = blockIdx.x * 256 + threadIdx.x;
  if (t < 65536) {  // PQP: NKT=16, kt<8 -> -P (sym), kt>=8 -> Qt
    const int l = t >> 14, c = t & 16383;
    const int ntile = c >> 10, kt = (c >> 6) & 15, lb = c & 63;
    const int n = ntile * 16 + (lb & 15);
    const int kq = (lb >> 4) * 8;
    half8 h;
    if (kt < 8) {
      h = *(const half8*)&Ph[(size_t)l * 65536 + n * 256 + kt * 32 + kq];
#pragma unroll
      for (int j = 0; j < 8; ++j) h[j] = -h[j];
    } else {
      h = *(const half8*)&Qt[(size_t)l * 65536 + n * 256 + (kt - 8) * 32 + kq];
    }
    *(half8*)&PQP[(size_t)t * 8] = h;
  } else if (t < 90112) {  // RmP: NKT=8, B[n][k] = -0.9*Wt[n][k]
    const int tt = t - 65536;
    const int l = tt >> 13, c = tt & 8191;
    const int ntile = c >> 9, kt = (c >> 6) & 7, lb = c & 63;
    const int n = ntile * 16 + (lb & 15);
    const int k0 = kt * 32 + (lb >> 4) * 8;
    half8 h = *(const half8*)&Wt[(size_t)l * 65536 + n * 256 + k0];
#pragma unroll
    for (int j = 0; j < 8; ++j) h[j] = (_Float16)(-0.9f * (float)h[j]);
    *(half8*)&RmP[(size_t)tt * 8] = h;
  } else if (t < 98304) {  // WiP: NKT=8, B[n][k] = Wi[n][k]
    const int c = t - 90112;
    const int ntile = c >> 9, kt = (c >> 6) & 7, lb = c & 63;
    const int n = ntile * 16 + (lb & 15);
    const int k0 = kt * 32 + (lb >> 4) * 8;
    const float4 a = *(const float4*)&Wi[n * 256 + k0];
    const float4 b = *(const float4*)&Wi[n * 256 + k0 + 4];
    half8 h;
    h[0] = (_Float16)a.x; h[1] = (_Float16)a.y; h[2] = (_Float16)a.z; h[3] = (_Float16)a.w;
    h[4] = (_Float16)b.x; h[5] = (_Float16)b.y; h[6] = (_Float16)b.z; h[7] = (_Float16)b.w;
    *(half8*)&WiP[(size_t)c * 8] = h;
  } else {  // WoP: NKT=8, classes padded to 16
    const int c = t - 98304;  // 0..511
    const int kt = c >> 6, lb = c & 63;
    const int n = lb & 15;
    const int k0 = kt * 32 + (lb >> 4) * 8;
    half8 h;
#pragma unroll
    for (int j = 0; j < 8; ++j) h[j] = (_Float16)((n < 10) ? Wo[n * 256 + k0 + j] : 0.f);
    *(half8*)&WoP[(size_t)c * 8] = h;
  }
}

// ================= fused persistent batch kernel =============================

// FRAGMENT-PACKED A-tile layout (R13): fragment f = kt*4 + mi, 1024B each;
// within fragment slot = MFMA lane, 16B/slot. All LDS accesses are
// compile-time offsets from a per-thread base.
// R14 geometry: wave tile 64x64 (mi=4, ni=4), 4 waves, 64-row slab.
// R15 structure: bf ring preloaded by caller across counted-wait barriers.
// R16: __launch_bounds__(256,1). The R15 regression was allocator-pinned
// 128 VGPR + 75MB spill: hipcc refuses >128 regs under (256,2) even though
// LDS (64KB -> 2 blocks/CU = 8 waves/CU) already caps occupancy identically
// for any VGPR <= 256. (256,1) lets it allocate the ~200 live regs
// (R7 precedent: picked exactly 256 under this bound). Zero occupancy cost.
// WRITE_SIZE remains the spill tell.

// preload ring slots 0..2 for the next GEMM phase
template <int NKT>
__device__ __forceinline__ void preB(const _Float16* __restrict__ Bp,
                                     half8 bf[4][4], int wave, int lane) {
#pragma unroll
  for (int s = 0; s < 3; ++s)
#pragma unroll
    for (int ni = 0; ni < 4; ++ni)
      bf[s][ni] = *(const half8*)&Bp[(((wave * 4 + ni) * NKT + s) * 64 + lane) * 8];
}

template <int NKT, bool DUAL>
__device__ __forceinline__ void gemm_k(const _Float16* __restrict__ Bp,
                                       const _Float16* A1, const _Float16* A2,
                                       f32x4* acc, half8 bf[4][4],
                                       int wave, int lane) {
  const char* a1b = (const char*)A1 + lane * 16;
  const char* a2b = (const char*)A2 + lane * 16;
#pragma unroll
  for (int kt = 0; kt < NKT; ++kt) {
    const int s = kt & 3;
    if (kt + 3 < NKT) {
#pragma unroll
      for (int ni = 0; ni < 4; ++ni)
        bf[(kt + 3) & 3][ni] =
            *(const half8*)&Bp[(((wave * 4 + ni) * NKT + kt + 3) * 64 + lane) * 8];
    }
    const char* Ab = (DUAL && kt >= NKT / 2) ? a2b : a1b;
    const int akt = DUAL ? (kt & (NKT / 2 - 1)) : kt;
    half8 af[4];
#pragma unroll
    for (int mi = 0; mi < 4; ++mi)
      af[mi] = *(const half8*)(Ab + (akt * 4 + mi) * 1024);
    __builtin_amdgcn_s_setprio(1);
#pragma unroll
    for (int mi = 0; mi < 4; ++mi)
#pragma unroll
      for (int ni = 0; ni < 4; ++ni)
        acc[mi * 4 + ni] = __builtin_amdgcn_mfma_f32_16x16x32_f16(
            bf[s][ni], af[mi], acc[mi * 4 + ni], 0, 0, 0);
    __builtin_amdgcn_s_setprio(0);
  }
}

// 64-row slab, 4 waves (256 thr), 2 blocks/CU (LDS 64KB), 2 waves/SIMD.
__global__ __launch_bounds__(256, 1) void k_fused(
    const float* __restrict__ x, const _Float16* __restrict__ WiP,
    const _Float16* __restrict__ PQP, const _Float16* __restrict__ RmP,
    const _Float16* __restrict__ WoP, const float* __restrict__ bi,
    const float* __restrict__ b1, const float* __restrict__ b2,
    const float* __restrict__ b3, const float* __restrict__ b4,
    const float* __restrict__ crm, const float* __restrict__ bo,
    float* __restrict__ out) {
  __shared__ __align__(16) _Float16 A1[64 * 256];
  __shared__ __align__(16) _Float16 A2[64 * 256];
  const int tid = threadIdx.x;
  const int wave = tid >> 6, lane = tid & 63;
  const int quad = lane >> 4, l16 = lane & 15;
  const int m0 = blockIdx.x * 64;

  // ---- stage x: fp32 HBM -> fp16 fragment-packed LDS (A1) ----
#pragma unroll
  for (int kk = 0; kk < 2; ++kk) {
    const int kt = wave + kk * 4;
#pragma unroll
    for (int mi = 0; mi < 4; ++mi) {
      const size_t gb = (size_t)(m0 + mi * 16 + l16) * 256 + kt * 32 + quad * 8;
      const float4 a = *(const float4*)&x[gb];
      const float4 b = *(const float4*)&x[gb + 4];
      half8 h;
      h[0] = (_Float16)a.x; h[1] = (_Float16)a.y; h[2] = (_Float16)a.z; h[3] = (_Float16)a.w;
      h[4] = (_Float16)b.x; h[5] = (_Float16)b.y; h[6] = (_Float16)b.z; h[7] = (_Float16)b.w;
      *(half8*)((char*)A1 + ((kt * 4 + mi) * 64 + lane) * 16) = h;
    }
  }

  f32x4 acc[16];
  const f32x4 zero = {0.f, 0.f, 0.f, 0.f};
  half4v uph[16];
  half8 ring[4][4];

  // ring for GEMM0 issued BEFORE the stage barrier (loads fly across it)
  preB<8>(WiP, ring, wave, lane);
  bar_lds();

  // per-thread epilogue base: wave owns cols [wave*64, wave*64+64) ->
  // addr = base + (ni>>1)*4096 + mi*1024 + (ni&1)*512
  const int ebase = wave * 8192 + (quad >> 1) * 256 + l16 * 16 + (quad & 1) * 8;
  char* e1 = (char*)A1 + ebase;
  char* e2 = (char*)A2 + ebase;

  // ---- GEMM0: z = x@WiT ; A1 = r1 = z+bi+0.1*b1 ; A2 = r2 = tanh(z+bi) ----
#pragma unroll
  for (int t = 0; t < 16; ++t) acc[t] = zero;
  gemm_k<8, false>(WiP, A1, A1, acc, ring, wave, lane);
  // bias first (in-order vmcnt: waiting on these leaves ring outstanding),
  // then next-phase ring — both in flight across the two barriers below.
  f32x4 bi4[4], b14[4];
#pragma unroll
  for (int ni = 0; ni < 4; ++ni) {
    const int col0 = wave * 64 + ni * 16 + quad * 4;
    bi4[ni] = *(const f32x4*)&bi[col0];
    b14[ni] = *(const f32x4*)&b1[col0];
  }
  preB<16>(PQP, ring, wave, lane);
  bar_lds();  // protect A1 overwrite (other waves done reading)
#pragma unroll
  for (int ni = 0; ni < 4; ++ni) {
#pragma unroll
    for (int mi = 0; mi < 4; ++mi) {
      const int off = (ni >> 1) * 4096 + mi * 1024 + (ni & 1) * 512;
      half4v h1, h2;
#pragma unroll
      for (int r = 0; r < 4; ++r) {
        const float z = acc[mi * 4 + ni][r] + bi4[ni][r];
        h1[r] = (_Float16)(z + DTC * b14[ni][r]);
        h2[r] = (_Float16)fast_tanh(z);
      }
      *(half4v*)(e1 + off) = h1;
      *(half4v*)(e2 + off) = h2;
    }
  }
  bar_lds();

  // ---- 4 transport layers ----
#pragma unroll 1
  for (int l = 0; l < 4; ++l) {
    // u' = r1@Pm + r2@Q   (K=512); ring preloaded by previous epilogue
#pragma unroll
    for (int t = 0; t < 16; ++t) acc[t] = zero;
    gemm_k<16, true>(PQP + (size_t)l * 131072, A1, A2, acc, ring, wave, lane);
    const float* bn = (l == 0) ? b2 : (l == 1) ? b3 : b4;
    f32x4 bn4[4];
#pragma unroll
    for (int ni = 0; ni < 4; ++ni) {
      bn4[ni] = zero;
      if (l < 3) bn4[ni] = DTC * (*(const f32x4*)&bn[wave * 64 + ni * 16 + quad * 4]);
    }
    if (l < 3) preB<8>(RmP + (size_t)l * 65536, ring, wave, lane);
    bar_lds();
#pragma unroll
    for (int ni = 0; ni < 4; ++ni) {
#pragma unroll
      for (int mi = 0; mi < 4; ++mi) {
        const int off = (ni >> 1) * 4096 + mi * 1024 + (ni & 1) * 512;
        half4v hu, h1;
#pragma unroll
        for (int r = 0; r < 4; ++r) {
          const float u = acc[mi * 4 + ni][r];
          hu[r] = (_Float16)u;
          h1[r] = (_Float16)(u + bn4[ni][r]);
        }
        uph[mi * 4 + ni] = hu;
        *(half4v*)(e1 + off) = h1;   // r1 for next layer / v'-GEMM input
      }
    }
    bar_lds();
    if (l < 3) {
      // v' = r1_next@Rm - crm - r2_old ; new r2 = (v' + 10 tanh u')/11
#pragma unroll
      for (int t = 0; t < 16; ++t) acc[t] = zero;
      gemm_k<8, false>(RmP + (size_t)l * 65536, A1, A1, acc, ring, wave, lane);
      f32x4 cc4[4];
#pragma unroll
      for (int ni = 0; ni < 4; ++ni)
        cc4[ni] = *(const f32x4*)&crm[l * 256 + wave * 64 + ni * 16 + quad * 4];
      preB<16>(PQP + (size_t)(l + 1) * 131072, ring, wave, lane);
      // no barrier needed before v-epilogue: v-GEMM read only A1; the
      // epilogue touches only this thread's own A2 slots.
#pragma unroll
      for (int ni = 0; ni < 4; ++ni) {
#pragma unroll
        for (int mi = 0; mi < 4; ++mi) {
          const int off = (ni >> 1) * 4096 + mi * 1024 + (ni & 1) * 512;
          const half4v r2o = *(const half4v*)(e2 + off);
          half4v nr2;
#pragma unroll
          for (int r = 0; r < 4; ++r) {
            const float vp = acc[mi * 4 + ni][r] - cc4[ni][r] - (float)r2o[r];
            nr2[r] = (_Float16)((vp + 10.f * fast_tanh((float)uph[mi * 4 + ni][r])) * (1.f / 11.f));
          }
          *(half4v*)(e2 + off) = nr2;
        }
      }
      bar_lds();
    }
  }

  // ---- head: logits = z@Wo^T + bo (swapped MFMA); softmax ----
  // layer-3 epilogue wrote A1 = u'; last bar_lds in the loop synced it.
  {
    f32x4 acch = zero;
#pragma unroll
    for (int kt = 0; kt < 8; ++kt) {
      const half8 af = *(const half8*)((const char*)A1 +
                                       ((kt * 4 + wave) * 64 + lane) * 16);
      const half8 bfr = *(const half8*)&WoP[(kt * 64 + lane) * 8];
      acch = __builtin_amdgcn_mfma_f32_16x16x32_f16(bfr, af, acch, 0, 0, 0);
    }
    float v4[4];
    float mx = -3.0e38f;
#pragma unroll
    for (int r = 0; r < 4; ++r) {
      const int cls = quad * 4 + r;
      const float v = acch[r] + ((cls < 10) ? bo[cls] : -3.0e38f);
      v4[r] = v;
      mx = fmaxf(mx, v);
    }
    mx = fmaxf(mx, __shfl_xor(mx, 16, 64));
    mx = fmaxf(mx, __shfl_xor(mx, 32, 64));
    float e4[4], s = 0.f;
#pragma unroll
    for (int r = 0; r < 4; ++r) {
      e4[r] = __expf(v4[r] - mx);
      s += e4[r];
    }
    s += __shfl_xor(s, 16, 64);
    s += __shfl_xor(s, 32, 64);
    const float rs = __builtin_amdgcn_rcpf(s);
    float* op = &out[(size_t)(m0 + wave * 16 + l16) * 10 + quad * 4];
    if (quad < 2) {
      f32x2 p0 = {e4[0] * rs, e4[1] * rs};
      f32x2 p1 = {e4[2] * rs, e4[3] * rs};
      *(f32x2*)op = p0;
      *(f32x2*)(op + 2) = p1;
    } else if (quad == 2) {
      f32x2 p0 = {e4[0] * rs, e4[1] * rs};
      *(f32x2*)op = p0;
    }
  }
}

// ================= launcher ==================================================

extern "C" void kernel_launch(void* const* d_in, const int* in_sizes, int n_in,
                              void* d_out, int out_size, void* d_ws, size_t ws_size,
                              hipStream_t stream) {
  const float* x  = (const float*)d_in[0];
  const float* Wi = (const float*)d_in[1];
  const float* bi = (const float*)d_in[2];
  const float* W[4] = {(const float*)d_in[3], (const float*)d_in[5],
                       (const float*)d_in[7], (const float*)d_in[9]};
  const float* b[4] = {(const float*)d_in[4], (const float*)d_in[6],
                       (const float*)d_in[8], (const float*)d_in[10]};
  const float* Wo = (const float*)d_in[11];
  const float* bo = (const float*)d_in[12];
  float* out = (float*)d_out;

  const int Bsz = in_sizes[0] / 256;  // 32768

  _Float16* hb = (_Float16*)d_ws;
  _Float16* WiP = hb;                   // 65536
  _Float16* WoP = hb + 65536;           // 4096
  _Float16* PQP = hb + 69632;           // 524288
  _Float16* RmP = hb + 593920;          // 196608
  _Float16* Wh  = hb + 790528;          // 262144
  _Float16* Wt  = hb + 1052672;         // 262144
  _Float16* Eh  = hb + 1314816;         // 262144
  _Float16* Ph  = hb + 1576960;         // 262144
  _Float16* Qt  = hb + 1839104;         // 262144
  float* crm = (float*)(hb + 2101248);  // 768 floats

  const dim3 g64(4, 4, 4);
  k_prep<<<387, 256, 0, stream>>>(W[0], W[1], W[2], W[3], b[1], b[2], b[3],
                                  Wh, Wt, crm);
  k_smm3<<<g64, 256, 0, stream>>>(Wh, Wh, nullptr, Eh, 0.01f, 0);  // E = DT^2 W W^T
  k_smm3<<<g64, 256, 0, stream>>>(Eh, Eh, Eh, Ph, 1.0f, 1);        // P = I - E + E^2
  k_smm3<<<g64, 256, 0, stream>>>(Ph, Wt, nullptr, Qt, DTC, 0);    // Qt = 0.1 P@W
  k_pack<<<386, 256, 0, stream>>>(Ph, Qt, Wt, Wi, Wo, PQP, RmP, WiP, WoP);

  k_fused<<<Bsz / 64, 256, 0, stream>>>(x, WiP, PQP, RmP, WoP, bi,
                                        b[0], b[1], b[2], b[3], crm, bo, out);
}

// Round 17
// 179.014 us; speedup vs baseline: 1.1730x; 1.0923x over previous
//
#include <hip/hip_runtime.h>
#include <math.h>

#define DTC 0.1f

typedef _Float16 half8 __attribute__((ext_vector_type(8)));
typedef _Float16 half4v __attribute__((ext_vector_type(4)));
typedef float f32x4 __attribute__((ext_vector_type(4)));
typedef float f32x2 __attribute__((ext_vector_type(2)));

__device__ __forceinline__ float fast_tanh(float x) {
  const float e = __expf(2.f * x);
  const float r = __builtin_amdgcn_rcpf(e + 1.f);
  return fmaf(-2.f, r, 1.f);
}

// ================= precompute =================================================

// ONE kernel for: Wt = fp16(W^T) (bids 0..255), crm (bids 256..258),
// E = 0.01 W W^T in fp16 (bids 259..322; reads fp32 W, converts inline —
// numerically identical to the old Wh path). Replaces k_prep + smm3(E):
// the 5-kernel serial prep chain was ~26us/launch of pure latency.
__global__ __launch_bounds__(256) void k_prep2(
    const float* __restrict__ W0, const float* __restrict__ W1,
    const float* __restrict__ W2, const float* __restrict__ W3,
    const float* __restrict__ b2, const float* __restrict__ b3,
    const float* __restrict__ b4,
    _Float16* __restrict__ Wt, float* __restrict__ crm,
    _Float16* __restrict__ Eh) {
  const float* Ws[4] = {W0, W1, W2, W3};
  const int bid = blockIdx.x, tid = threadIdx.x;
  if (bid < 256) {  // Wt transpose
    __shared__ float sh[32][33];
    const int l = bid >> 6, t64 = bid & 63;
    const int r0 = (t64 >> 3) * 32, c0 = (t64 & 7) * 32;
    const float* W = Ws[l];
    const int i = tid >> 5, j = tid & 31;
#pragma unroll
    for (int p = 0; p < 4; ++p)
      sh[p * 8 + i][j] = W[(r0 + p * 8 + i) * 256 + c0 + j];
    __syncthreads();
#pragma unroll
    for (int p = 0; p < 4; ++p)
      Wt[l * 65536 + (c0 + p * 8 + i) * 256 + r0 + j] = (_Float16)sh[j][p * 8 + i];
  } else if (bid < 259) {  // crm
    const int l = bid - 256;
    const float* W = Ws[l];
    const float* b = (l == 0) ? b2 : (l == 1) ? b3 : b4;
    float s = 0.f;
#pragma unroll 8
    for (int k = 0; k < 256; ++k) s = fmaf(b[k], W[k * 256 + tid], s);
    crm[l * 256 + tid] = -0.09f * s;
  } else {  // E = 0.01 W W^T, 64 blocks (l, my, nx)
    const int eb = bid - 259;
    const int l = eb >> 4;
    const float* W = Ws[l];
    _Float16* El = Eh + (size_t)l * 65536;
    const int wave = tid >> 6, lane = tid & 63;
    const int quad = lane >> 4, l16 = lane & 15;
    const int m0 = (((eb >> 2) & 3)) * 64 + wave * 16, n0 = (eb & 3) * 64;
    f32x4 acc[4] = {};
    auto ld8 = [&](int row, int k0) {
      const float4 a = *(const float4*)&W[row * 256 + k0];
      const float4 b = *(const float4*)&W[row * 256 + k0 + 4];
      half8 h;
      h[0] = (_Float16)a.x; h[1] = (_Float16)a.y; h[2] = (_Float16)a.z; h[3] = (_Float16)a.w;
      h[4] = (_Float16)b.x; h[5] = (_Float16)b.y; h[6] = (_Float16)b.z; h[7] = (_Float16)b.w;
      return h;
    };
#pragma unroll
    for (int kt = 0; kt < 8; ++kt) {
      const int k0 = kt * 32 + quad * 8;
      const half8 af = ld8(m0 + l16, k0);
#pragma unroll
      for (int ni = 0; ni < 4; ++ni) {
        const half8 bf = ld8(n0 + ni * 16 + l16, k0);
        acc[ni] = __builtin_amdgcn_mfma_f32_16x16x32_f16(af, bf, acc[ni], 0, 0, 0);
      }
    }
#pragma unroll
    for (int ni = 0; ni < 4; ++ni)
#pragma unroll
      for (int r = 0; r < 4; ++r) {
        const int row = m0 + quad * 4 + r, col = n0 + ni * 16 + l16;
        El[row * 256 + col] = (_Float16)(0.01f * acc[ni][r]);
      }
  }
}

// C = scale*(A@B^T) [+ I - Eadd]   per layer (blockIdx.z), 256x256, fp16 rm out
__global__ __launch_bounds__(256) void k_smm3(const _Float16* __restrict__ A,
                                              const _Float16* __restrict__ B,
                                              const _Float16* __restrict__ Eadd,
                                              _Float16* __restrict__ C,
                                              float scale, int addI) {
  const int tid = threadIdx.x, wave = tid >> 6, lane = tid & 63;
  const int quad = lane >> 4, l16 = lane & 15;
  const int l = blockIdx.z;
  const _Float16* Al = A + (size_t)l * 65536;
  const _Float16* Bl = B + (size_t)l * 65536;
  _Float16* Cl = C + (size_t)l * 65536;
  const int m0 = blockIdx.y * 64 + wave * 16, n0 = blockIdx.x * 64;
  f32x4 acc[4] = {};
#pragma unroll
  for (int kt = 0; kt < 8; ++kt) {
    const half8 af = *(const half8*)&Al[(m0 + l16) * 256 + kt * 32 + quad * 8];
#pragma unroll
    for (int ni = 0; ni < 4; ++ni) {
      const half8 bf = *(const half8*)&Bl[(n0 + ni * 16 + l16) * 256 + kt * 32 + quad * 8];
      acc[ni] = __builtin_amdgcn_mfma_f32_16x16x32_f16(af, bf, acc[ni], 0, 0, 0);
    }
  }
#pragma unroll
  for (int ni = 0; ni < 4; ++ni)
#pragma unroll
    for (int r = 0; r < 4; ++r) {
      const int row = m0 + quad * 4 + r, col = n0 + ni * 16 + l16;
      float v = scale * acc[ni][r];
      if (addI) v += (row == col ? 1.f : 0.f) - (float)(Eadd + (size_t)l * 65536)[row * 256 + col];
      Cl[row * 256 + col] = (_Float16)v;
    }
}

// Destination-mapped coalesced packing of all B-frag weight buffers.
// chunk = 16B of 8 halves; packed idx = ((ntile*NKT+kt)*64 + lane)*8 + j
// holds B[n=ntile*16+(lane&15)][k=kt*32+(lane>>4)*8+j]
__global__ __launch_bounds__(256) void k_pack(
    const _Float16* __restrict__ Ph, const _Float16* __restrict__ Qt,
    const _Float16* __restrict__ Wt, const float* __restrict__ Wi,
    const float* __restrict__ Wo,
    _Float16* __restrict__ PQP, _Float16* __restrict__ RmP,
    _Float16* __restrict__ WiP, _Float16* __restrict__ WoP) {
  const int t = blockIdx.x * 256 + threadIdx.x;
  if (t < 65536) {  // PQP: NKT=16, kt<8 -> -P (sym), kt>=8 -> Qt
    const int l = t >> 14, c = t & 16383;
    const int ntile = c >> 10, kt = (c >> 6) & 15, lb = c & 63;
    const int n = ntile * 16 + (lb & 15);
    const int kq = (lb >> 4) * 8;
    half8 h;
    if (kt < 8) {
      h = *(const half8*)&Ph[(size_t)l * 65536 + n * 256 + kt * 32 + kq];
#pragma unroll
      for (int j = 0; j < 8; ++j) h[j] = -h[j];
    } else {
      h = *(const half8*)&Qt[(size_t)l * 65536 + n * 256 + (kt - 8) * 32 + kq];
    }
    *(half8*)&PQP[(size_t)t * 8] = h;
  } else if (t < 90112) {  // RmP: NKT=8, B[n][k] = -0.9*Wt[n][k]
    const int tt = t - 65536;
    const int l = tt >> 13, c = tt & 8191;
    const int ntile = c >> 9, kt = (c >> 6) & 7, lb = c & 63;
    const int n = ntile * 16 + (lb & 15);
    const int k0 = kt * 32 + (lb >> 4) * 8;
    half8 h = *(const half8*)&Wt[(size_t)l * 65536 + n * 256 + k0];
#pragma unroll
    for (int j = 0; j < 8; ++j) h[j] = (_Float16)(-0.9f * (float)h[j]);
    *(half8*)&RmP[(size_t)tt * 8] = h;
  } else if (t < 98304) {  // WiP: NKT=8, B[n][k] = Wi[n][k]
    const int c = t - 90112;
    const int ntile = c >> 9, kt = (c >> 6) & 7, lb = c & 63;
    const int n = ntile * 16 + (lb & 15);
    const int k0 = kt * 32 + (lb >> 4) * 8;
    const float4 a = *(const float4*)&Wi[n * 256 + k0];
    const float4 b = *(const float4*)&Wi[n * 256 + k0 + 4];
    half8 h;
    h[0] = (_Float16)a.x; h[1] = (_Float16)a.y; h[2] = (_Float16)a.z; h[3] = (_Float16)a.w;
    h[4] = (_Float16)b.x; h[5] = (_Float16)b.y; h[6] = (_Float16)b.z; h[7] = (_Float16)b.w;
    *(half8*)&WiP[(size_t)c * 8] = h;
  } else {  // WoP: NKT=8, classes padded to 16
    const int c = t - 98304;  // 0..511
    const int kt = c >> 6, lb = c & 63;
    const int n = lb & 15;
    const int k0 = kt * 32 + (lb >> 4) * 8;
    half8 h;
#pragma unroll
    for (int j = 0; j < 8; ++j) h[j] = (_Float16)((n < 10) ? Wo[n * 256 + k0 + j] : 0.f);
    *(half8*)&WoP[(size_t)c * 8] = h;
  }
}

// ================= fused persistent batch kernel =============================

// FRAGMENT-PACKED A-tile layout (R13): fragment f = kt*4 + mi, 1024B each;
// within fragment slot = MFMA lane, 16B/slot. All LDS accesses are
// compile-time offsets from a per-thread base.
// R14 champion geometry (verbatim): wave tile 64x64 (mi=4, ni=4), 4 waves,
// 64-row slab, 2 blocks/CU, VGPR ~120 (8 waves/CU). The R15/R16 pipeline
// arc proved cross-barrier ring preload needs ~190 live regs -> drops
// HW residency below 8 waves/CU: net loss. This structure is the sweet spot.
template <int NKT, bool DUAL>
__device__ __forceinline__ void gemm_k(const _Float16* __restrict__ Bp,
                                       const _Float16* A1, const _Float16* A2,
                                       f32x4* acc, int wave, int lane) {
  half8 bf[4][4];
  auto loadB = [&](int kt, int s) {
#pragma unroll
    for (int ni = 0; ni < 4; ++ni)
      bf[s][ni] = *(const half8*)&Bp[(((wave * 4 + ni) * NKT + kt) * 64 + lane) * 8];
  };
  loadB(0, 0);
  loadB(1, 1);
  loadB(2, 2);
  const char* a1b = (const char*)A1 + lane * 16;
  const char* a2b = (const char*)A2 + lane * 16;
#pragma unroll
  for (int kt = 0; kt < NKT; ++kt) {
    const int s = kt & 3;
    if (kt + 3 < NKT) loadB(kt + 3, (kt + 3) & 3);
    const char* Ab = (DUAL && kt >= NKT / 2) ? a2b : a1b;
    const int akt = DUAL ? (kt & (NKT / 2 - 1)) : kt;
    half8 af[4];
#pragma unroll
    for (int mi = 0; mi < 4; ++mi)
      af[mi] = *(const half8*)(Ab + (akt * 4 + mi) * 1024);
    __builtin_amdgcn_s_setprio(1);
#pragma unroll
    for (int mi = 0; mi < 4; ++mi)
#pragma unroll
      for (int ni = 0; ni < 4; ++ni)
        acc[mi * 4 + ni] = __builtin_amdgcn_mfma_f32_16x16x32_f16(
            bf[s][ni], af[mi], acc[mi * 4 + ni], 0, 0, 0);
    __builtin_amdgcn_s_setprio(0);
  }
}

// 64-row slab, 4 waves (256 thr), 2 blocks/CU (LDS 64KB), 2 waves/SIMD.
__global__ __launch_bounds__(256, 2) void k_fused(
    const float* __restrict__ x, const _Float16* __restrict__ WiP,
    const _Float16* __restrict__ PQP, const _Float16* __restrict__ RmP,
    const _Float16* __restrict__ WoP, const float* __restrict__ bi,
    const float* __restrict__ b1, const float* __restrict__ b2,
    const float* __restrict__ b3, const float* __restrict__ b4,
    const float* __restrict__ crm, const float* __restrict__ bo,
    float* __restrict__ out) {
  __shared__ __align__(16) _Float16 A1[64 * 256];
  __shared__ __align__(16) _Float16 A2[64 * 256];
  const int tid = threadIdx.x;
  const int wave = tid >> 6, lane = tid & 63;
  const int quad = lane >> 4, l16 = lane & 15;
  const int m0 = blockIdx.x * 64;

  // ---- stage x: fp32 HBM -> fp16 fragment-packed LDS (A1) ----
  // wave w fills fragments kt=w and kt=w+4 (mi=0..3).
#pragma unroll
  for (int kk = 0; kk < 2; ++kk) {
    const int kt = wave + kk * 4;
#pragma unroll
    for (int mi = 0; mi < 4; ++mi) {
      const size_t gb = (size_t)(m0 + mi * 16 + l16) * 256 + kt * 32 + quad * 8;
      const float4 a = *(const float4*)&x[gb];
      const float4 b = *(const float4*)&x[gb + 4];
      half8 h;
      h[0] = (_Float16)a.x; h[1] = (_Float16)a.y; h[2] = (_Float16)a.z; h[3] = (_Float16)a.w;
      h[4] = (_Float16)b.x; h[5] = (_Float16)b.y; h[6] = (_Float16)b.z; h[7] = (_Float16)b.w;
      *(half8*)((char*)A1 + ((kt * 4 + mi) * 64 + lane) * 16) = h;
    }
  }
  __syncthreads();

  f32x4 acc[16];
  const f32x4 zero = {0.f, 0.f, 0.f, 0.f};
  half4v uph[16];

  // per-thread epilogue base: wave owns cols [wave*64, wave*64+64) ->
  // fragments 2*wave + (ni>>1); addr = base + (ni>>1)*4096 + mi*1024 + (ni&1)*512
  const int ebase = wave * 8192 + (quad >> 1) * 256 + l16 * 16 + (quad & 1) * 8;
  char* e1 = (char*)A1 + ebase;
  char* e2 = (char*)A2 + ebase;

  // ---- GEMM0: z = x@WiT ; A1 = r1 = z+bi+0.1*b1 ; A2 = r2 = tanh(z+bi) ----
#pragma unroll
  for (int t = 0; t < 16; ++t) acc[t] = zero;
  gemm_k<8, false>(WiP, A1, A1, acc, wave, lane);
  __syncthreads();
#pragma unroll
  for (int ni = 0; ni < 4; ++ni) {
    const int col0 = wave * 64 + ni * 16 + quad * 4;
    const f32x4 bi4 = *(const f32x4*)&bi[col0];
    const f32x4 b14 = *(const f32x4*)&b1[col0];
#pragma unroll
    for (int mi = 0; mi < 4; ++mi) {
      const int off = (ni >> 1) * 4096 + mi * 1024 + (ni & 1) * 512;
      half4v h1, h2;
#pragma unroll
      for (int r = 0; r < 4; ++r) {
        const float z = acc[mi * 4 + ni][r] + bi4[r];
        h1[r] = (_Float16)(z + DTC * b14[r]);
        h2[r] = (_Float16)fast_tanh(z);
      }
      *(half4v*)(e1 + off) = h1;
      *(half4v*)(e2 + off) = h2;
    }
  }
  __syncthreads();

  // ---- 4 transport layers ----
#pragma unroll 1
  for (int l = 0; l < 4; ++l) {
    // u' = r1@Pm + r2@Q   (K=512)
#pragma unroll
    for (int t = 0; t < 16; ++t) acc[t] = zero;
    gemm_k<16, true>(PQP + (size_t)l * 131072, A1, A2, acc, wave, lane);
    __syncthreads();
    const float* bn = (l == 0) ? b2 : (l == 1) ? b3 : b4;
#pragma unroll
    for (int ni = 0; ni < 4; ++ni) {
      const int col0 = wave * 64 + ni * 16 + quad * 4;
      f32x4 bn4 = zero;
      if (l < 3) bn4 = DTC * (*(const f32x4*)&bn[col0]);
#pragma unroll
      for (int mi = 0; mi < 4; ++mi) {
        const int off = (ni >> 1) * 4096 + mi * 1024 + (ni & 1) * 512;
        half4v hu, h1;
#pragma unroll
        for (int r = 0; r < 4; ++r) {
          const float u = acc[mi * 4 + ni][r];
          hu[r] = (_Float16)u;
          h1[r] = (_Float16)(u + bn4[r]);
        }
        uph[mi * 4 + ni] = hu;
        *(half4v*)(e1 + off) = h1;   // r1 for next layer / v'-GEMM input
      }
    }
    __syncthreads();
    if (l < 3) {
      // v' = r1_next@Rm - crm - r2_old ; new r2 = (v' + 10 tanh u')/11
      // r2_old re-read from A2 (own elems) just before overwrite (R11).
#pragma unroll
      for (int t = 0; t < 16; ++t) acc[t] = zero;
      gemm_k<8, false>(RmP + (size_t)l * 65536, A1, A1, acc, wave, lane);
#pragma unroll
      for (int ni = 0; ni < 4; ++ni) {
        const int col0 = wave * 64 + ni * 16 + quad * 4;
        const f32x4 cc4 = *(const f32x4*)&crm[l * 256 + col0];
#pragma unroll
        for (int mi = 0; mi < 4; ++mi) {
          const int off = (ni >> 1) * 4096 + mi * 1024 + (ni & 1) * 512;
          const half4v r2o = *(const half4v*)(e2 + off);
          half4v nr2;
#pragma unroll
          for (int r = 0; r < 4; ++r) {
            const float vp = acc[mi * 4 + ni][r] - cc4[r] - (float)r2o[r];
            nr2[r] = (_Float16)((vp + 10.f * fast_tanh((float)uph[mi * 4 + ni][r])) * (1.f / 11.f));
          }
          *(half4v*)(e2 + off) = nr2;
        }
      }
      __syncthreads();
    }
  }

  // ---- head: logits = z@Wo^T + bo (swapped MFMA); softmax ----
  // rows 0..63 -> fragment mi = wave; af addr const-offset per kt.
  {
    f32x4 acch = zero;
#pragma unroll
    for (int kt = 0; kt < 8; ++kt) {
      const half8 af = *(const half8*)((const char*)A1 +
                                       ((kt * 4 + wave) * 64 + lane) * 16);
      const half8 bfr = *(const half8*)&WoP[(kt * 64 + lane) * 8];
      acch = __builtin_amdgcn_mfma_f32_16x16x32_f16(bfr, af, acch, 0, 0, 0);
    }
    float v4[4];
    float mx = -3.0e38f;
#pragma unroll
    for (int r = 0; r < 4; ++r) {
      const int cls = quad * 4 + r;
      const float v = acch[r] + ((cls < 10) ? bo[cls] : -3.0e38f);
      v4[r] = v;
      mx = fmaxf(mx, v);
    }
    mx = fmaxf(mx, __shfl_xor(mx, 16, 64));
    mx = fmaxf(mx, __shfl_xor(mx, 32, 64));
    float e4[4], s = 0.f;
#pragma unroll
    for (int r = 0; r < 4; ++r) {
      e4[r] = __expf(v4[r] - mx);
      s += e4[r];
    }
    s += __shfl_xor(s, 16, 64);
    s += __shfl_xor(s, 32, 64);
    const float rs = __builtin_amdgcn_rcpf(s);
    float* op = &out[(size_t)(m0 + wave * 16 + l16) * 10 + quad * 4];
    if (quad < 2) {
      f32x2 p0 = {e4[0] * rs, e4[1] * rs};
      f32x2 p1 = {e4[2] * rs, e4[3] * rs};
      *(f32x2*)op = p0;
      *(f32x2*)(op + 2) = p1;
    } else if (quad == 2) {
      f32x2 p0 = {e4[0] * rs, e4[1] * rs};
      *(f32x2*)op = p0;
    }
  }
}

// ================= launcher ==================================================

extern "C" void kernel_launch(void* const* d_in, const int* in_sizes, int n_in,
                              void* d_out, int out_size, void* d_ws, size_t ws_size,
                              hipStream_t stream) {
  const float* x  = (const float*)d_in[0];
  const float* Wi = (const float*)d_in[1];
  const float* bi = (const float*)d_in[2];
  const float* W[4] = {(const float*)d_in[3], (const float*)d_in[5],
                       (const float*)d_in[7], (const float*)d_in[9]};
  const float* b[4] = {(const float*)d_in[4], (const float*)d_in[6],
                       (const float*)d_in[8], (const float*)d_in[10]};
  const float* Wo = (const float*)d_in[11];
  const float* bo = (const float*)d_in[12];
  float* out = (float*)d_out;

  const int Bsz = in_sizes[0] / 256;  // 32768

  _Float16* hb = (_Float16*)d_ws;
  _Float16* WiP = hb;                   // 65536
  _Float16* WoP = hb + 65536;           // 4096
  _Float16* PQP = hb + 69632;           // 524288
  _Float16* RmP = hb + 593920;          // 196608
  _Float16* Wt  = hb + 790528;          // 262144
  _Float16* Eh  = hb + 1052672;         // 262144
  _Float16* Ph  = hb + 1314816;         // 262144
  _Float16* Qt  = hb + 1576960;         // 262144
  float* crm = (float*)(hb + 1839104);  // 768 floats

  const dim3 g64(4, 4, 4);
  // 5-launch prep chain (was 6): k_prep2 computes Wt + crm + E in one go.
  k_prep2<<<323, 256, 0, stream>>>(W[0], W[1], W[2], W[3], b[1], b[2], b[3],
                                   Wt, crm, Eh);
  k_smm3<<<g64, 256, 0, stream>>>(Eh, Eh, Eh, Ph, 1.0f, 1);        // P = I - E + E^2
  k_smm3<<<g64, 256, 0, stream>>>(Ph, Wt, nullptr, Qt, DTC, 0);    // Qt = 0.1 P@W
  k_pack<<<386, 256, 0, stream>>>(Ph, Qt, Wt, Wi, Wo, PQP, RmP, WiP, WoP);

  k_fused<<<Bsz / 64, 256, 0, stream>>>(x, WiP, PQP, RmP, WoP, bi,
                                        b[0], b[1], b[2], b[3], crm, bo, out);
}